// Round 5
// baseline (603.748 us; speedup 1.0000x reference)
//
#include <hip/hip_runtime.h>
#include <stdint.h>

// Two-pass structure: each pass is a PURE-direction memory stream.
//   Pass 1 (read-only):  scan a_bytes/b_bytes one-hots -> 4B out-index per word
//                        into d_ws (65536 words x 4B = 256 KB).
//   Pass 2 (write-only): expand indices -> one-hot [B,4,256] output.
// Rationale: fused one-shot waves convoyed read-burst/write-burst phases and
// plateaued at 3 TB/s; unidirectional grid-stride streams should each run at
// the ~6.3 TB/s class ceiling. NT stores removed (R4: consistently -8%).

typedef float f32x4 __attribute__((ext_vector_type(4)));

__device__ __forceinline__ uint32_t row_index(f32x4 v) {
    const bool nx = v.x != 0.0f, ny = v.y != 0.0f, nz = v.z != 0.0f, nw = v.w != 0.0f;
    const unsigned long long m  = __ballot(nx | ny | nz | nw);
    const unsigned long long m0 = __ballot(ny | nw);          // bit0 of sub-offset
    const unsigned long long m1 = __ballot(nz | nw);          // bit1 of sub-offset
    const int src = __ffsll(m) - 1;                           // lane holding the 1
    return ((uint32_t)src << 2) |
           (uint32_t)((m0 >> src) & 1ull) |
           ((uint32_t)((m1 >> src) & 1ull) << 1);
}

__device__ __forceinline__ f32x4 onehot4(int j, uint32_t oi) {
    f32x4 r;
    r.x = ((uint32_t)j     == oi) ? 1.0f : 0.0f;
    r.y = ((uint32_t)j + 1 == oi) ? 1.0f : 0.0f;
    r.z = ((uint32_t)j + 2 == oi) ? 1.0f : 0.0f;
    r.w = ((uint32_t)j + 3 == oi) ? 1.0f : 0.0f;
    return r;
}

// ---- Pass 1: read-only scan, one wave per word, grid-stride ----
__global__ __launch_bounds__(256) void pass1_idx(
    const f32x4* __restrict__ a4, const f32x4* __restrict__ b4,
    uint32_t* __restrict__ idx, int n_words)
{
    const int lane    = threadIdx.x & 63;
    const int wave    = (blockIdx.x << 2) | (threadIdx.x >> 6);
    const int n_waves = gridDim.x << 2;
    for (int word = wave; word < n_words; word += n_waves) {
        const long base = (long)word * 256 + lane;
        const f32x4 av0 = a4[base];       const f32x4 bv0 = b4[base];
        const f32x4 av1 = a4[base + 64];  const f32x4 bv1 = b4[base + 64];
        const f32x4 av2 = a4[base + 128]; const f32x4 bv2 = b4[base + 128];
        const f32x4 av3 = a4[base + 192]; const f32x4 bv3 = b4[base + 192];
        const uint32_t aw = row_index(av0)        | (row_index(av1) << 8) |
                            (row_index(av2) << 16) | (row_index(av3) << 24);
        const uint32_t bw = row_index(bv0)        | (row_index(bv1) << 8) |
                            (row_index(bv2) << 16) | (row_index(bv3) << 24);
        const uint32_t o = (aw + bw) ^ aw;   // ripple-add then per-byte xor with a
        if (lane == 0) idx[word] = o;
    }
}

// ---- Pass 2: write-only one-hot expansion, one wave per word, grid-stride ----
__global__ __launch_bounds__(256) void pass2_write(
    const uint32_t* __restrict__ idx, f32x4* __restrict__ o4, int n_words)
{
    const int lane    = threadIdx.x & 63;
    const int wave    = (blockIdx.x << 2) | (threadIdx.x >> 6);
    const int n_waves = gridDim.x << 2;
    for (int word = wave; word < n_words; word += n_waves) {
        const uint32_t o = idx[word];       // 4B/word, L2/L3-resident
        const long base = (long)word * 256 + lane;
        const int j = lane * 4;
        o4[base]       = onehot4(j,  o        & 255u);
        o4[base + 64]  = onehot4(j, (o >> 8)  & 255u);
        o4[base + 128] = onehot4(j, (o >> 16) & 255u);
        o4[base + 192] = onehot4(j, (o >> 24) & 255u);
    }
}

// ---- Fallback: fused single pass (used only if d_ws is too small) ----
__global__ __launch_bounds__(256) void vm_fused(
    const f32x4* __restrict__ a4, const f32x4* __restrict__ b4,
    f32x4* __restrict__ o4, int n_words)
{
    const int word = (blockIdx.x << 2) | (threadIdx.x >> 6);
    const int lane = threadIdx.x & 63;
    if (word >= n_words) return;
    const long base = (long)word * 256 + lane;
    const f32x4 av0 = a4[base];       const f32x4 av1 = a4[base + 64];
    const f32x4 av2 = a4[base + 128]; const f32x4 av3 = a4[base + 192];
    const f32x4 bv0 = b4[base];       const f32x4 bv1 = b4[base + 64];
    const f32x4 bv2 = b4[base + 128]; const f32x4 bv3 = b4[base + 192];
    const uint32_t aw = row_index(av0)        | (row_index(av1) << 8) |
                        (row_index(av2) << 16) | (row_index(av3) << 24);
    const uint32_t bw = row_index(bv0)        | (row_index(bv1) << 8) |
                        (row_index(bv2) << 16) | (row_index(bv3) << 24);
    const uint32_t o = (aw + bw) ^ aw;
    const int j = lane * 4;
    o4[base]       = onehot4(j,  o        & 255u);
    o4[base + 64]  = onehot4(j, (o >> 8)  & 255u);
    o4[base + 128] = onehot4(j, (o >> 16) & 255u);
    o4[base + 192] = onehot4(j, (o >> 24) & 255u);
}

extern "C" void kernel_launch(void* const* d_in, const int* in_sizes, int n_in,
                              void* d_out, int out_size, void* d_ws, size_t ws_size,
                              hipStream_t stream)
{
    const f32x4* a4 = (const f32x4*)d_in[0];   // [B,4,256] one-hot
    const f32x4* b4 = (const f32x4*)d_in[1];
    f32x4* o4 = (f32x4*)d_out;                 // [B,4,256]
    const int n_words = in_sizes[0] / 1024;    // B

    if (ws_size >= (size_t)n_words * sizeof(uint32_t)) {
        uint32_t* idx = (uint32_t*)d_ws;
        pass1_idx <<<1024, 256, 0, stream>>>(a4, b4, idx, n_words);   // 4096 waves, 16 words each
        pass2_write<<<4096, 256, 0, stream>>>(idx, o4, n_words);      // 16384 waves, 4 words each
    } else {
        vm_fused<<<(n_words + 3) / 4, 256, 0, stream>>>(a4, b4, o4, n_words);
    }
}

// Round 6
// 590.616 us; speedup vs baseline: 1.0222x; 1.0222x over previous
//
#include <hip/hip_runtime.h>
#include <stdint.h>

// Single fused kernel, grid-stride, SOFTWARE-PIPELINED: each wave owns a
// strided set of words and always has the NEXT word's 8 float4 loads in
// flight while computing/storing the current word. This removes the
// per-iteration load-drain bubble that capped R1-R5 variants at ~3 TB/s
// (the harness's own fillBuffer sustains 6.5 TB/s at 10% occupancy, so the
// memory system is not the limit). NT stores intentionally absent (R4: -8%).

typedef float f32x4 __attribute__((ext_vector_type(4)));

__device__ __forceinline__ uint32_t row_index(f32x4 v) {
    const bool nx = v.x != 0.0f, ny = v.y != 0.0f, nz = v.z != 0.0f, nw = v.w != 0.0f;
    const unsigned long long m  = __ballot(nx | ny | nz | nw);
    const unsigned long long m0 = __ballot(ny | nw);          // bit0 of sub-offset
    const unsigned long long m1 = __ballot(nz | nw);          // bit1 of sub-offset
    const int src = __ffsll(m) - 1;                           // lane holding the 1
    return ((uint32_t)src << 2) |
           (uint32_t)((m0 >> src) & 1ull) |
           ((uint32_t)((m1 >> src) & 1ull) << 1);
}

__device__ __forceinline__ f32x4 onehot4(int j, uint32_t oi) {
    f32x4 r;
    r.x = ((uint32_t)j     == oi) ? 1.0f : 0.0f;
    r.y = ((uint32_t)j + 1 == oi) ? 1.0f : 0.0f;
    r.z = ((uint32_t)j + 2 == oi) ? 1.0f : 0.0f;
    r.w = ((uint32_t)j + 3 == oi) ? 1.0f : 0.0f;
    return r;
}

__global__ __launch_bounds__(256) void vm_pipe(
    const f32x4* __restrict__ a4,
    const f32x4* __restrict__ b4,
    f32x4* __restrict__ o4,
    int n_words)
{
    const int lane    = threadIdx.x & 63;
    const int wave    = (blockIdx.x << 2) | (threadIdx.x >> 6);
    const int n_waves = gridDim.x << 2;

    int word = wave;
    if (word >= n_words) return;

    // Prologue: current word's 8 vectors.
    long base = (long)word * 256 + lane;
    f32x4 a0 = a4[base], a1 = a4[base + 64], a2 = a4[base + 128], a3 = a4[base + 192];
    f32x4 b0 = b4[base], b1 = b4[base + 64], b2 = b4[base + 128], b3 = b4[base + 192];

    while (true) {
        const int  next  = word + n_waves;           // wave-uniform
        const bool more  = next < n_words;
        const long nbase = (long)next * 256 + lane;

        // Issue NEXT word's loads before consuming current regs, so the
        // vmcnt wait for the ballots leaves these 8 loads outstanding.
        f32x4 na0, na1, na2, na3, nb0, nb1, nb2, nb3;
        if (more) {
            na0 = a4[nbase];       na1 = a4[nbase + 64];
            na2 = a4[nbase + 128]; na3 = a4[nbase + 192];
            nb0 = b4[nbase];       nb1 = b4[nbase + 64];
            nb2 = b4[nbase + 128]; nb3 = b4[nbase + 192];
        }

        // Consume current word.
        const uint32_t aw = row_index(a0)        | (row_index(a1) << 8) |
                            (row_index(a2) << 16) | (row_index(a3) << 24);
        const uint32_t bw = row_index(b0)        | (row_index(b1) << 8) |
                            (row_index(b2) << 16) | (row_index(b3) << 24);
        const uint32_t o  = (aw + bw) ^ aw;   // ripple-carry add, then per-byte xor with a

        const int j = lane * 4;
        o4[base]       = onehot4(j,  o        & 255u);
        o4[base + 64]  = onehot4(j, (o >> 8)  & 255u);
        o4[base + 128] = onehot4(j, (o >> 16) & 255u);
        o4[base + 192] = onehot4(j, (o >> 24) & 255u);

        if (!more) break;
        word = next; base = nbase;
        a0 = na0; a1 = na1; a2 = na2; a3 = na3;
        b0 = nb0; b1 = nb1; b2 = nb2; b3 = nb3;
    }
}

extern "C" void kernel_launch(void* const* d_in, const int* in_sizes, int n_in,
                              void* d_out, int out_size, void* d_ws, size_t ws_size,
                              hipStream_t stream)
{
    const f32x4* a4 = (const f32x4*)d_in[0];   // [B,4,256] one-hot
    const f32x4* b4 = (const f32x4*)d_in[1];
    f32x4* o4 = (f32x4*)d_out;                 // [B,4,256]
    const int n_words = in_sizes[0] / 1024;    // B = 65536
    // 1024 blocks -> 4096 waves -> 16 words/wave: long-lived waves so the
    // pipeline prologue is amortized and loads stay continuously in flight.
    vm_pipe<<<1024, 256, 0, stream>>>(a4, b4, o4, n_words);
}